// Round 18
// baseline (1353.751 us; speedup 1.0000x reference)
//
#include <hip/hip_runtime.h>

typedef unsigned short u16;

#define DIMM   192
#define DEPTH  12
#define NHEAD  3
#define MLPD   768
#define NCLS   35
#define NTOK   99
#define TIMG   98
#define FIMG   40
#define NBATCH 512
#define MT     7

// LDS layout (u16 element offsets)
#define XS_S 200
#define QH_S 72
#define VT_S 136
#define P_S  136
#define XS0  0
#define QH0  22400
#define KH0  30464
#define VT0  38528
#define P0   47232
#define RR_BYTE 124928
#define SMEM_BYTES 128512

// Q pre-scale: dhead^-0.5 * log2(e) so softmax can use exp2 directly
#define QSCALE 0.1803368801111243f

typedef __attribute__((ext_vector_type(8))) __bf16 bf8;
typedef __attribute__((ext_vector_type(4))) float  f4;
typedef __attribute__((ext_vector_type(2))) unsigned u32x2;

__device__ __forceinline__ float b2f(u16 u){
  union { float f; unsigned u; } v; v.u = ((unsigned)u) << 16; return v.f;
}
__device__ __forceinline__ float blo(unsigned u){
  union { float f; unsigned u; } v; v.u = u << 16; return v.f;
}
__device__ __forceinline__ float bhi(unsigned u){
  union { float f; unsigned u; } v; v.u = u & 0xffff0000u; return v.f;
}
__device__ __forceinline__ u16 f2b(float f){
  __bf16 h = (__bf16)f;
  union { __bf16 h; u16 u; } v; v.h = h;
  return v.u;
}
__device__ __forceinline__ u32x2 pack4(f4 a){
  u32x2 p;
  p.x = (unsigned)f2b(a[0]) | ((unsigned)f2b(a[1]) << 16);
  p.y = (unsigned)f2b(a[2]) | ((unsigned)f2b(a[3]) << 16);
  return p;
}
__device__ __forceinline__ f4 mm(bf8 a, bf8 b, f4 c){
  return __builtin_amdgcn_mfma_f32_16x16x32_bf16(a, b, c, 0, 0, 0);
}
__device__ __forceinline__ float gelu_f(float x){
  float z = x * 0.7071067811865476f;
  float az = fabsf(z);
  float t = 1.0f / (1.0f + 0.3275911f * az);
  float poly = ((((1.061405429f*t - 1.453152027f)*t + 1.421413741f)*t
                 - 0.284496736f)*t + 0.254829592f)*t;
  float erfv = 1.0f - poly * __expf(-az*az);
  erfv = (z < 0.0f) ? -erfv : erfv;
  return 0.5f * x * (1.0f + erfv);
}
__device__ __forceinline__ f4 gelu4(f4 a, float4 fb){
  f4 g;
  g[0] = gelu_f(a[0] + fb.x);
  g[1] = gelu_f(a[1] + fb.y);
  g[2] = gelu_f(a[2] + fb.z);
  g[3] = gelu_f(a[3] + fb.w);
  return g;
}

// Pre-permute weights: f32 [layers][K][N] -> bf16 fragment order
extern "C" __global__ void permw(const float* __restrict__ src, u16* __restrict__ dst,
                                 int total, int KT, int NT, int realK, int Ndim){
  int i = blockIdx.x * 256 + threadIdx.x;
  if (i >= total) return;
  int j = i & 7, l = (i >> 3) & 63;
  int rest = i >> 9;
  int kt = rest % KT; rest /= KT;
  int nt = rest % NT; int layer = rest / NT;
  int k = kt*32 + (l>>4)*8 + j;
  int n = nt*16 + (l&15);
  float v = (k < realK) ? src[((size_t)layer*realK + k)*Ndim + n] : 0.0f;
  union { float f; unsigned u; } w; w.f = v;
  unsigned r = w.u + 0x7FFFu + ((w.u >> 16) & 1u);
  dst[i] = (u16)(r >> 16);
}

extern "C" __global__
__attribute__((amdgpu_flat_work_group_size(768,768), amdgpu_waves_per_eu(3,3)))
void vit_main(
    const float* __restrict__ img,   const float* __restrict__ g_feat,
    const float* __restrict__ pos_emb,
    const float* __restrict__ ln1_g, const float* __restrict__ ln1_b,
    const float* __restrict__ ln2_g, const float* __restrict__ ln2_b,
    const float* __restrict__ out_b, const float* __restrict__ ff1_b,
    const float* __restrict__ ff2_b,
    const float* __restrict__ hln_g, const float* __restrict__ hln_b,
    const float* __restrict__ head_w, const float* __restrict__ head_b,
    const u16* __restrict__ wlin, const u16* __restrict__ wqkv,
    const u16* __restrict__ wout, const u16* __restrict__ wff1,
    const u16* __restrict__ wff2,
    float* __restrict__ out)
{
  extern __shared__ __align__(16) u16 sm[];
  float* rowred = (float*)((char*)sm + RR_BYTE);
  const int tid  = threadIdx.x;
  const int lane = tid & 63;
  const int wv   = tid >> 6;     // 0..11
  const int wm   = wv >> 2;      // M-group 0..2: tiles {0-2},{3-5},{6}
  const int wn   = wv & 3;       // N-group
  const int lg   = lane >> 4;
  const int lr   = lane & 15;
  const int b    = blockIdx.x;

  // ---- precomputed LDS base pointers ----
  u16* const pA  = sm + XS0 + (wm*48 + lr)*XS_S + lg*8;        // x A/B-frag: +mi*16*XS_S + kt*32
  u16* const pH  = sm + QH0 + (wm*48 + lr)*XS_S + lg*8;        // h frag
  u16* const pOA = sm + QH0 + (wm*48 + lr)*QH_S + lg*8;        // o/img frag
  u16* const pQS = sm + QH0 + (wm*48 + lr)*QH_S + wn*16 + lg*4;// Q^T b64 store (K at +KH0-QH0): +mi*16*QH_S
  u16* const pVS = sm + VT0 + (wn*16 + lr)*VT_S + wm*48 + lg*4;// V^T b64 store: +mi*16
  u16* const pQA = sm + QH0 + (wv*16 + lr)*QH_S + lg*8;        // Aq read (phase B, wv<7)
  u16* const pKB = sm + KH0 + lr*QH_S + lg*8;                  // K frag (phase B)
  u16* const pPT = sm + P0  + (wv*16 + lr)*P_S + lg*4;         // P b64 store (wv<7): +kt*16
  u16* const pPA = sm + P0  + (wv*16 + lr)*P_S + lg*8;         // Ap read (wv<7)
  u16* const pVB = sm + VT0 + lr*VT_S + lg*8;                  // V^T frag: +nt*16*VT_S + ks*32
  u16* const pOS = sm + QH0 + (wv*16 + lr)*QH_S + lg*4;        // o b64 store (wv<7): +nt*16
  u16* const pHS = sm + QH0 + (wm*48 + lr)*XS_S + wn*48 + lg*4;// h b64 store: +mi*16*XS_S + nt*16
  u16* const pXT = sm + XS0 + (wm*48 + lr)*XS_S + wn*48 + lg*4;// x epi b64 rw: +mi*16*XS_S + nt*16
  u16* const pXE = sm + XS0 + (wm*48 + lg*4)*XS_S + wn*48 + lr;// patch-embed scalar store

  // zero all LDS once (pad regions must stay 0 forever)
  for (int i = tid; i < SMEM_BYTES/4; i += 768) ((unsigned*)sm)[i] = 0u;
  __syncthreads();

  const f4 zero4 = {0.f,0.f,0.f,0.f};

  // Transposed LN epilogue: acc[mi][nt][r] = feature (wn*48+nt*16+lg*4+r) of token (wm*48+mi*16+lr)
  auto epilogue_ln = [&](f4 (&acc)[3][3],
                         const float* gptr, const float* bptr, const float* biasptr){
    float4 g4[3], b4[3], ob4[3];
#pragma unroll
    for (int nt = 0; nt < 3; ++nt) {
      int c = wn*48 + nt*16 + lg*4;
      g4[nt]  = *(const float4*)&gptr[c];
      b4[nt]  = *(const float4*)&bptr[c];
      ob4[nt] = *(const float4*)&biasptr[c];
    }
#pragma unroll
    for (int mi = 0; mi < 3; ++mi) {
      if (wm < 2 || mi == 0) {
        const int row = wm*48 + mi*16 + lr;
        float s1 = 0.f, s2 = 0.f;
#pragma unroll
        for (int nt = 0; nt < 3; ++nt) {
          u32x2 xo = *(const u32x2*)(pXT + mi*16*XS_S + nt*16);
          float v0 = acc[mi][nt][0] + ob4[nt].x + blo(xo.x);
          float v1 = acc[mi][nt][1] + ob4[nt].y + bhi(xo.x);
          float v2 = acc[mi][nt][2] + ob4[nt].z + blo(xo.y);
          float v3 = acc[mi][nt][3] + ob4[nt].w + bhi(xo.y);
          acc[mi][nt][0] = v0; acc[mi][nt][1] = v1;
          acc[mi][nt][2] = v2; acc[mi][nt][3] = v3;
          s1 += (v0+v1)+(v2+v3);
          s2 += v0*v0; s2 += v1*v1; s2 += v2*v2; s2 += v3*v3;
        }
        s1 += __shfl_xor(s1,16); s2 += __shfl_xor(s2,16);
        s1 += __shfl_xor(s1,32); s2 += __shfl_xor(s2,32);
        if (lg == 0) {
          float2 pr; pr.x = s1; pr.y = s2;
          *(float2*)&rowred[row*8 + wn*2] = pr;
        }
      }
    }
    __syncthreads();
#pragma unroll
    for (int mi = 0; mi < 3; ++mi) {
      if (wm < 2 || mi == 0) {
        const int row = wm*48 + mi*16 + lr;
        float4 q0 = *(const float4*)&rowred[row*8];
        float4 q1 = *(const float4*)&rowred[row*8 + 4];
        float S1 = (q0.x + q0.z) + (q1.x + q1.z);
        float S2 = (q0.y + q0.w) + (q1.y + q1.w);
        float mean = S1 * (1.0f/DIMM);
        float var  = S2 * (1.0f/DIMM) - mean*mean;
        float rs = rsqrtf(var + 1e-5f);
        if (row < NTOK) {
#pragma unroll
          for (int nt = 0; nt < 3; ++nt) {
            f4 y;
            y[0] = (acc[mi][nt][0]-mean)*rs*g4[nt].x + b4[nt].x;
            y[1] = (acc[mi][nt][1]-mean)*rs*g4[nt].y + b4[nt].y;
            y[2] = (acc[mi][nt][2]-mean)*rs*g4[nt].z + b4[nt].z;
            y[3] = (acc[mi][nt][3]-mean)*rs*g4[nt].w + b4[nt].w;
            *(u32x2*)(pXT + mi*16*XS_S + nt*16) = pack4(y);
          }
        }
      }
    }
    __syncthreads();
  };

  // ---- patch embed: stage img (shifted +1 row; row0 = cls slot) into QH region ----
  const float* imgb = img + (size_t)b * (TIMG*FIMG);
  for (int i = tid; i < TIMG*FIMG; i += 768) {
    int r = i / FIMG, c = i - r*FIMG;
    sm[QH0 + (r+1)*QH_S + c] = f2b(imgb[i]);
  }
  __syncthreads();
  {
    const u16* wl = wlin + (size_t)(wn*3)*2*512 + lane*8;
    bf8 Bf[3][2];
#pragma unroll
    for (int nt = 0; nt < 3; ++nt)
#pragma unroll
      for (int kt = 0; kt < 2; ++kt)
        Bf[nt][kt] = *(const bf8*)&wl[(nt*2+kt)*512];
#pragma unroll
    for (int mi = 0; mi < 3; ++mi) {
      if (wm < 2 || mi == 0) {
        bf8 Af[2];
#pragma unroll
        for (int kt = 0; kt < 2; ++kt)
          Af[kt] = *(const bf8*)&pOA[mi*16*QH_S + kt*32];
#pragma unroll
        for (int nt = 0; nt < 3; ++nt) {
          f4 a = zero4;
#pragma unroll
          for (int kt = 0; kt < 2; ++kt) a = mm(Af[kt], Bf[nt][kt], a);
          int col = wn*48 + nt*16 + lr;
#pragma unroll
          for (int r = 0; r < 4; ++r) {
            int row = wm*48 + mi*16 + lg*4 + r;
            if (row < NTOK) {
              float v = a[r] + pos_emb[row*DIMM + col] + (row==0 ? g_feat[col] : 0.f);
              pXE[(mi*16+r)*XS_S + nt*16] = f2b(v);
            }
          }
        }
      }
    }
  }
  __syncthreads();

  for (int L = 0; L < DEPTH; ++L) {
    const u16* wq = wqkv + (size_t)L*36*6*512;
    // ================= attention =================
    f4 oacc[3][3];
#pragma unroll
    for (int mi = 0; mi < 3; ++mi)
#pragma unroll
      for (int nt = 0; nt < 3; ++nt) oacc[mi][nt] = zero4;

    // Bq/Bk live across head iterations: loaded for head 0 here (cold),
    // prefetched for head h+1 during phase D of head h (covered by D compute).
    bf8 Bq[6], Bk[6];
    {
      const u16* wpq = wq + ((size_t)(     wn)*6)*512 + lane*8;
      const u16* wpk = wq + ((size_t)(12 + wn)*6)*512 + lane*8;
#pragma unroll
      for (int kt = 0; kt < 6; ++kt) {
        Bq[kt] = *(const bf8*)&wpq[kt*512];
        Bk[kt] = *(const bf8*)&wpk[kt*512];
      }
    }

#pragma unroll
    for (int h = 0; h < NHEAD; ++h) {
      // (A1) fused Q+K pass: A-frags read ONCE, feed both transposed GEMMs (Bq/Bk preloaded)
      {
#pragma unroll
        for (int mi = 0; mi < 3; ++mi) {
          if (wm < 2 || mi == 0) {
            bf8 Af[6];
#pragma unroll
            for (int kt = 0; kt < 6; ++kt)
              Af[kt] = *(const bf8*)&pA[mi*16*XS_S + kt*32];
            f4 aq = zero4, ak = zero4;
#pragma unroll
            for (int kt = 0; kt < 6; ++kt) {
              aq = mm(Bq[kt], Af[kt], aq);   // (xWq)^T
              ak = mm(Bk[kt], Af[kt], ak);   // (xWk)^T
            }
            aq = aq * QSCALE;                // Q pre-scaled (incl log2e)
            *(u32x2*)(pQS + mi*16*QH_S) = pack4(aq);
            *(u32x2*)(pQS + (KH0-QH0) + mi*16*QH_S) = pack4(ak);
          }
        }
      }
      // (A2) V pass (normal orientation; transposed dest, b64)
      {
        const u16* wpv = wq + ((size_t)(24 + h*4 + wn)*6)*512 + lane*8;
        bf8 Bv[6];
#pragma unroll
        for (int kt = 0; kt < 6; ++kt) Bv[kt] = *(const bf8*)&wpv[kt*512];
#pragma unroll
        for (int mi = 0; mi < 3; ++mi) {
          if (wm < 2 || mi == 0) {
            bf8 Af[6];
#pragma unroll
            for (int kt = 0; kt < 6; ++kt)
              Af[kt] = *(const bf8*)&pA[mi*16*XS_S + kt*32];
            f4 av = zero4;
#pragma unroll
            for (int kt = 0; kt < 6; ++kt) av = mm(Af[kt], Bv[kt], av);
            *(u32x2*)(pVS + mi*16) = pack4(av);
          }
        }
      }
      __syncthreads();

      // HOISTED: out-proj B-fragments loaded HERE so their L2 latency hides under
      // phase B (waves 0-6) or the barrier wait (waves 7-11).
      bf8 Bo[3][2];
      {
        const u16* wp = wout + (((size_t)(L*12 + wn*3)*6) + h*2)*512 + lane*8;
#pragma unroll
        for (int nt = 0; nt < 3; ++nt)
#pragma unroll
          for (int ks = 0; ks < 2; ++ks)
            Bo[nt][ks] = *(const bf8*)&wp[(nt*6 + ks)*512];
      }

      // (B): S^T = K·Q^T per key-tile; softmax lane-local over keys; P b64; O = (PV)^T
      if (wv < MT) {
        bf8 Aq[2];
#pragma unroll
        for (int ks = 0; ks < 2; ++ks)
          Aq[ks] = *(const bf8*)&pQA[ks*32];
        f4 sT[7];                      // sT[kt][r]: key kt*16+lg*4+r, query lr
#pragma unroll
        for (int kt = 0; kt < 7; ++kt) {
          f4 a = zero4;
#pragma unroll
          for (int ks = 0; ks < 2; ++ks) {
            bf8 Bk2 = *(const bf8*)&pKB[kt*16*QH_S + ks*32];
            a = mm(Bk2, Aq[ks], a);    // S^T
          }
          sT[kt] = a;
        }
        // keys valid: kt<6 all; kt==6 only lg==0 && r<3 (keys 96..98)
        float m = -1e30f;
#pragma unroll
        for (int kt = 0; kt < 6; ++kt)
#pragma unroll
          for (int r = 0; r < 4; ++r) m = fmaxf(m, sT[kt][r]);
        if (lg == 0) { m = fmaxf(m, fmaxf(sT[6][0], fmaxf(sT[6][1], sT[6][2]))); }
        m = fmaxf(m, __shfl_xor(m, 16));
        m = fmaxf(m, __shfl_xor(m, 32));
        float pT[7][4]; float sum = 0.f;
#pragma unroll
        for (int kt = 0; kt < 6; ++kt)
#pragma unroll
          for (int r = 0; r < 4; ++r) { float p = exp2f(sT[kt][r] - m); pT[kt][r] = p; sum += p; }
#pragma unroll
        for (int r = 0; r < 4; ++r) {
          float p = (lg == 0 && r < 3) ? exp2f(sT[6][r] - m) : 0.f;
          pT[6][r] = p; sum += p;
        }
        sum += __shfl_xor(sum, 16);
        sum += __shfl_xor(sum, 32);
        float inv = 1.0f / sum;
#pragma unroll
        for (int kt = 0; kt < 7; ++kt) {
          f4 pp;
          pp[0] = pT[kt][0]*inv; pp[1] = pT[kt][1]*inv;
          pp[2] = pT[kt][2]*inv; pp[3] = pT[kt][3]*inv;
          *(u32x2*)(pPT + kt*16) = pack4(pp);
        }
        asm volatile("" ::: "memory");  // keep P writes before fragment reads
        bf8 Ap[4];
#pragma unroll
        for (int ks = 0; ks < 4; ++ks)
          Ap[ks] = *(const bf8*)&pPA[ks*32];
#pragma unroll
        for (int nt = 0; nt < 4; ++nt) {
          f4 a = zero4;
#pragma unroll
          for (int ks = 0; ks < 4; ++ks) {
            bf8 Bv2 = *(const bf8*)&pVB[nt*16*VT_S + ks*32];
            a = mm(Bv2, Ap[ks], a);    // (PV)^T
          }
          *(u32x2*)(pOS + nt*16) = pack4(a);  // o[qtoken][dhead] b64
        }
      }
      __syncthreads();

      // PREFETCH next head's Bq/Bk during phase D (covered by D compute + barrier)
      if (h < NHEAD-1) {
        const u16* wpq = wq + ((size_t)((h+1)*4 + wn)*6)*512 + lane*8;
        const u16* wpk = wq + ((size_t)(12 + (h+1)*4 + wn)*6)*512 + lane*8;
#pragma unroll
        for (int kt = 0; kt < 6; ++kt) {
          Bq[kt] = *(const bf8*)&wpq[kt*512];
          Bk[kt] = *(const bf8*)&wpk[kt*512];
        }
      }

      // (D) out-proj TRANSPOSED accumulate: oaccT += (o_h · out_w)^T  (Bo pre-loaded)
      {
#pragma unroll
        for (int mi = 0; mi < 3; ++mi) {
          if (wm < 2 || mi == 0) {
            bf8 Ao[2];
#pragma unroll
            for (int ks = 0; ks < 2; ++ks)
              Ao[ks] = *(const bf8*)&pOA[mi*16*QH_S + ks*32];
#pragma unroll
            for (int nt = 0; nt < 3; ++nt)
#pragma unroll
              for (int ks = 0; ks < 2; ++ks)
                oacc[mi][nt] = mm(Bo[nt][ks], Ao[ks], oacc[mi][nt]);
          }
        }
      }
      __syncthreads();
    } // heads

    epilogue_ln(oacc, ln1_g + L*DIMM, ln1_b + L*DIMM, out_b + L*DIMM);

    // ================= MLP =================
    f4 facc[3][3];
#pragma unroll
    for (int mi = 0; mi < 3; ++mi)
#pragma unroll
      for (int nt = 0; nt < 3; ++nt) facc[mi][nt] = zero4;

    for (int blk = 0; blk < 4; ++blk) {
      { // GEMM1 + gelu, TRANSPOSED -> h[token][mlpcol] b64 stores (nt-outer, B[6] only)
        const u16* wp = wff1 + ((size_t)(L*48 + blk*12 + wn*3)*6)*512 + lane*8;
        const float* fbp = ff1_b + L*MLPD + blk*192 + wn*48;
#pragma unroll
        for (int nt = 0; nt < 3; ++nt) {
          bf8 B[6];
#pragma unroll
          for (int kt = 0; kt < 6; ++kt) B[kt] = *(const bf8*)&wp[(nt*6+kt)*512];
          float4 fb4 = *(const float4*)&fbp[nt*16 + lg*4];
#pragma unroll
          for (int mi = 0; mi < 3; ++mi) {
            if (wm < 2 || mi == 0) {
              bf8 Af[6];
#pragma unroll
              for (int kt = 0; kt < 6; ++kt)
                Af[kt] = *(const bf8*)&pA[mi*16*XS_S + kt*32];
              f4 a = zero4;
#pragma unroll
              for (int kt = 0; kt < 6; ++kt) a = mm(B[kt], Af[kt], a);  // (xW1)^T
              *(u32x2*)(pHS + mi*16*XS_S + nt*16) = pack4(gelu4(a, fb4));
            }
          }
        }
      }
      __syncthreads();
      { // GEMM2 TRANSPOSED accumulate; B-pair holding (no gelu temps: spill-safe)
        const u16* wp = wff2 + ((size_t)(L*12 + wn*3)*24 + blk*6)*512 + lane*8;
        { // group nt = {0,1}
          bf8 B0[6], B1[6];
#pragma unroll
          for (int kt = 0; kt < 6; ++kt) {
            B0[kt] = *(const bf8*)&wp[kt*512];
            B1[kt] = *(const bf8*)&wp[(24+kt)*512];
          }
#pragma unroll
          for (int mi = 0; mi < 3; ++mi) {
            if (wm < 2 || mi == 0) {
              bf8 Ah[6];
#pragma unroll
              for (int kt = 0; kt < 6; ++kt)
                Ah[kt] = *(const bf8*)&pH[mi*16*XS_S + kt*32];
#pragma unroll
              for (int kt = 0; kt < 6; ++kt) {
                facc[mi][0] = mm(B0[kt], Ah[kt], facc[mi][0]);
                facc[mi][1] = mm(B1[kt], Ah[kt], facc[mi][1]);
              }
            }
          }
        }
        { // group nt = {2}
          bf8 B2[6];
#pragma unroll
          for (int kt = 0; kt < 6; ++kt)
            B2[kt] = *(const bf8*)&wp[(48+kt)*512];
#pragma unroll
          for (int mi = 0; mi < 3; ++mi) {
            if (wm < 2 || mi == 0) {
              bf8 Ah[6];
#pragma unroll
              for (int kt = 0; kt < 6; ++kt)
                Ah[kt] = *(const bf8*)&pH[mi*16*XS_S + kt*32];
#pragma unroll
              for (int kt = 0; kt < 6; ++kt)
                facc[mi][2] = mm(B2[kt], Ah[kt], facc[mi][2]);
            }
          }
        }
      }
      __syncthreads();
    }

    epilogue_ln(facc, ln2_g + L*DIMM, ln2_b + L*DIMM, ff2_b + L*DIMM);
  } // layers

  // ================= head =================
  float* yv = rowred;
  if (wv == 0) {
    float x0 = b2f(sm[XS0 + lane]);
    float x1 = b2f(sm[XS0 + 64 + lane]);
    float x2 = b2f(sm[XS0 + 128 + lane]);
    float s1 = x0+x1+x2;
    float s2 = x0*x0 + x1*x1 + x2*x2;
#pragma unroll
    for (int d = 1; d < 64; d <<= 1) { s1 += __shfl_xor(s1, d); s2 += __shfl_xor(s2, d); }
    float mean = s1*(1.0f/DIMM), var = s2*(1.0f/DIMM) - mean*mean;
    float rs = rsqrtf(var + 1e-5f);
    yv[lane]      = (x0-mean)*rs*hln_g[lane]      + hln_b[lane];
    yv[64+lane]   = (x1-mean)*rs*hln_g[64+lane]   + hln_b[64+lane];
    yv[128+lane]  = (x2-mean)*rs*hln_g[128+lane]  + hln_b[128+lane];
  }
  __syncthreads();
  if (tid < NCLS) {
    float acc = head_b[tid];
    for (int k = 0; k < DIMM; ++k) acc += yv[k] * head_w[k*NCLS + tid];
    out[(size_t)b*NCLS + tid] = acc;
  }
}

extern "C" void kernel_launch(void* const* d_in, const int* in_sizes, int n_in,
                              void* d_out, int out_size, void* d_ws, size_t ws_size,
                              hipStream_t stream) {
  const float* img    = (const float*)d_in[0];
  const float* lin_w  = (const float*)d_in[1];
  const float* g_feat = (const float*)d_in[2];
  const float* pos_emb= (const float*)d_in[3];
  const float* ln1_g  = (const float*)d_in[4];
  const float* ln1_b  = (const float*)d_in[5];
  const float* ln2_g  = (const float*)d_in[6];
  const float* ln2_b  = (const float*)d_in[7];
  const float* qkv_w  = (const float*)d_in[8];
  const float* out_w  = (const float*)d_in[9];
  const float* out_b  = (const float*)d_in[10];
  const float* ff1_w  = (const float*)d_in[11];
  const float* ff1_b  = (const float*)d_in[12];
  const float* ff2_w  = (const float*)d_in[13];
  const float* ff2_b  = (const float*)d_in[14];
  const float* hln_g  = (const float*)d_in[15];
  const float* hln_b  = (const float*)d_in[16];
  const float* head_w = (const float*)d_in[17];
  const float* head_b = (const float*)d_in[18];

  u16* ws   = (u16*)d_ws;
  u16* wlin = ws;                   // 1*12*2*512    = 12288
  u16* wqkv = wlin + 12288;         // 12*36*6*512   = 1327104
  u16* wout = wqkv + 1327104;       // 12*12*6*512   = 442368
  u16* wff1 = wout + 442368;        // 12*48*6*512   = 1769472
  u16* wff2 = wff1 + 1769472;       // 12*12*24*512  = 1769472

  struct PermArgs { const float* src; u16* dst; int layers, Kdim, Ndim, realK; };
  const PermArgs pa[5] = {
    { lin_w, wlin, 1, 64, 192, 40 },
    { qkv_w, wqkv, 12, 192, 576, 192 },
    { out_w, wout, 12, 192, 192, 192 },
    { ff1_w, wff1, 12, 192, 768, 192 },
    { ff2_w, wff2, 12, 768, 192, 768 },
  };
  for (int i = 0; i < 5; ++i) {
    int total = pa[i].layers * (pa[i].Ndim/16) * (pa[i].Kdim/32) * 512;
    hipLaunchKernelGGL(permw, dim3((total + 255)/256), dim3(256), 0, stream,
                       pa[i].src, pa[i].dst, total, pa[i].Kdim/32, pa[i].Ndim/16,
                       pa[i].realK, pa[i].Ndim);
  }

  hipFuncSetAttribute(reinterpret_cast<const void*>(vit_main),
                      hipFuncAttributeMaxDynamicSharedMemorySize, SMEM_BYTES);

  hipLaunchKernelGGL(vit_main, dim3(NBATCH), dim3(768), SMEM_BYTES, stream,
                     img, g_feat, pos_emb, ln1_g, ln1_b, ln2_g, ln2_b,
                     out_b, ff1_b, ff2_b, hln_g, hln_b, head_w, head_b,
                     wlin, wqkv, wout, wff1, wff2, (float*)d_out);
}

// Round 19
// 1321.535 us; speedup vs baseline: 1.0244x; 1.0244x over previous
//
#include <hip/hip_runtime.h>

typedef unsigned short u16;

#define DIMM   192
#define DEPTH  12
#define NHEAD  3
#define MLPD   768
#define NCLS   35
#define NTOK   99
#define TIMG   98
#define FIMG   40
#define NBATCH 512
#define MT     7

// LDS layout (u16 element offsets)
#define XS_S 200
#define QH_S 72
#define VT_S 136
#define P_S  136
#define XS0  0
#define QH0  22400
#define KH0  30464
#define VT0  38528
#define P0   47232
#define RR_BYTE 124928
#define SMEM_BYTES 128512

// Q pre-scale: dhead^-0.5 * log2(e) so softmax can use exp2 directly
#define QSCALE 0.1803368801111243f

typedef __attribute__((ext_vector_type(8))) __bf16 bf8;
typedef __attribute__((ext_vector_type(4))) float  f4;
typedef __attribute__((ext_vector_type(2))) unsigned u32x2;

__device__ __forceinline__ float b2f(u16 u){
  union { float f; unsigned u; } v; v.u = ((unsigned)u) << 16; return v.f;
}
__device__ __forceinline__ float blo(unsigned u){
  union { float f; unsigned u; } v; v.u = u << 16; return v.f;
}
__device__ __forceinline__ float bhi(unsigned u){
  union { float f; unsigned u; } v; v.u = u & 0xffff0000u; return v.f;
}
__device__ __forceinline__ u16 f2b(float f){
  __bf16 h = (__bf16)f;
  union { __bf16 h; u16 u; } v; v.h = h;
  return v.u;
}
__device__ __forceinline__ u32x2 pack4(f4 a){
  u32x2 p;
  p.x = (unsigned)f2b(a[0]) | ((unsigned)f2b(a[1]) << 16);
  p.y = (unsigned)f2b(a[2]) | ((unsigned)f2b(a[3]) << 16);
  return p;
}
__device__ __forceinline__ f4 mm(bf8 a, bf8 b, f4 c){
  return __builtin_amdgcn_mfma_f32_16x16x32_bf16(a, b, c, 0, 0, 0);
}
__device__ __forceinline__ float gelu_f(float x){
  float z = x * 0.7071067811865476f;
  float az = fabsf(z);
  float t = 1.0f / (1.0f + 0.3275911f * az);
  float poly = ((((1.061405429f*t - 1.453152027f)*t + 1.421413741f)*t
                 - 0.284496736f)*t + 0.254829592f)*t;
  float erfv = 1.0f - poly * __expf(-az*az);
  erfv = (z < 0.0f) ? -erfv : erfv;
  return 0.5f * x * (1.0f + erfv);
}
__device__ __forceinline__ f4 gelu4(f4 a, float4 fb){
  f4 g;
  g[0] = gelu_f(a[0] + fb.x);
  g[1] = gelu_f(a[1] + fb.y);
  g[2] = gelu_f(a[2] + fb.z);
  g[3] = gelu_f(a[3] + fb.w);
  return g;
}

// Pre-permute weights: f32 [layers][K][N] -> bf16 fragment order
extern "C" __global__ void permw(const float* __restrict__ src, u16* __restrict__ dst,
                                 int total, int KT, int NT, int realK, int Ndim){
  int i = blockIdx.x * 256 + threadIdx.x;
  if (i >= total) return;
  int j = i & 7, l = (i >> 3) & 63;
  int rest = i >> 9;
  int kt = rest % KT; rest /= KT;
  int nt = rest % NT; int layer = rest / NT;
  int k = kt*32 + (l>>4)*8 + j;
  int n = nt*16 + (l&15);
  float v = (k < realK) ? src[((size_t)layer*realK + k)*Ndim + n] : 0.0f;
  union { float f; unsigned u; } w; w.f = v;
  unsigned r = w.u + 0x7FFFu + ((w.u >> 16) & 1u);
  dst[i] = (u16)(r >> 16);
}

extern "C" __global__
__attribute__((amdgpu_flat_work_group_size(768,768), amdgpu_waves_per_eu(3,3)))
void vit_main(
    const float* __restrict__ img,   const float* __restrict__ g_feat,
    const float* __restrict__ pos_emb,
    const float* __restrict__ ln1_g, const float* __restrict__ ln1_b,
    const float* __restrict__ ln2_g, const float* __restrict__ ln2_b,
    const float* __restrict__ out_b, const float* __restrict__ ff1_b,
    const float* __restrict__ ff2_b,
    const float* __restrict__ hln_g, const float* __restrict__ hln_b,
    const float* __restrict__ head_w, const float* __restrict__ head_b,
    const u16* __restrict__ wlin, const u16* __restrict__ wqkv,
    const u16* __restrict__ wout, const u16* __restrict__ wff1,
    const u16* __restrict__ wff2,
    float* __restrict__ out)
{
  extern __shared__ __align__(16) u16 sm[];
  float* rowred = (float*)((char*)sm + RR_BYTE);
  const int tid  = threadIdx.x;
  const int lane = tid & 63;
  const int wv   = tid >> 6;     // 0..11
  const int wm   = wv >> 2;      // M-group 0..2: tiles {0-2},{3-5},{6}
  const int wn   = wv & 3;       // N-group
  const int lg   = lane >> 4;
  const int lr   = lane & 15;
  const int b    = blockIdx.x;

  // ---- precomputed LDS base pointers ----
  u16* const pA  = sm + XS0 + (wm*48 + lr)*XS_S + lg*8;        // x A/B-frag: +mi*16*XS_S + kt*32
  u16* const pH  = sm + QH0 + (wm*48 + lr)*XS_S + lg*8;        // h frag
  u16* const pOA = sm + QH0 + (wm*48 + lr)*QH_S + lg*8;        // o/img frag
  u16* const pQS = sm + QH0 + (wm*48 + lr)*QH_S + wn*16 + lg*4;// Q^T b64 store (K at +KH0-QH0): +mi*16*QH_S
  u16* const pVS = sm + VT0 + (wn*16 + lr)*VT_S + wm*48 + lg*4;// V^T b64 store: +mi*16
  u16* const pQA = sm + QH0 + (wv*16 + lr)*QH_S + lg*8;        // Aq read (phase B, wv<7)
  u16* const pKB = sm + KH0 + lr*QH_S + lg*8;                  // K frag (phase B)
  u16* const pPT = sm + P0  + (wv*16 + lr)*P_S + lg*4;         // P b64 store (wv<7): +kt*16
  u16* const pPA = sm + P0  + (wv*16 + lr)*P_S + lg*8;         // Ap read (wv<7)
  u16* const pVB = sm + VT0 + lr*VT_S + lg*8;                  // V^T frag: +nt*16*VT_S + ks*32
  u16* const pOS = sm + QH0 + (wv*16 + lr)*QH_S + lg*4;        // o b64 store (wv<7): +nt*16
  u16* const pHS = sm + QH0 + (wm*48 + lr)*XS_S + wn*48 + lg*4;// h b64 store: +mi*16*XS_S + nt*16
  u16* const pXT = sm + XS0 + (wm*48 + lr)*XS_S + wn*48 + lg*4;// x epi b64 rw: +mi*16*XS_S + nt*16
  u16* const pXE = sm + XS0 + (wm*48 + lg*4)*XS_S + wn*48 + lr;// patch-embed scalar store

  // zero all LDS once (pad regions must stay 0 forever)
  for (int i = tid; i < SMEM_BYTES/4; i += 768) ((unsigned*)sm)[i] = 0u;
  __syncthreads();

  const f4 zero4 = {0.f,0.f,0.f,0.f};

  // Transposed LN epilogue: acc[mi][nt][r] = feature (wn*48+nt*16+lg*4+r) of token (wm*48+mi*16+lr)
  auto epilogue_ln = [&](f4 (&acc)[3][3],
                         const float* gptr, const float* bptr, const float* biasptr){
    float4 g4[3], b4[3], ob4[3];
#pragma unroll
    for (int nt = 0; nt < 3; ++nt) {
      int c = wn*48 + nt*16 + lg*4;
      g4[nt]  = *(const float4*)&gptr[c];
      b4[nt]  = *(const float4*)&bptr[c];
      ob4[nt] = *(const float4*)&biasptr[c];
    }
#pragma unroll
    for (int mi = 0; mi < 3; ++mi) {
      if (wm < 2 || mi == 0) {
        const int row = wm*48 + mi*16 + lr;
        float s1 = 0.f, s2 = 0.f;
#pragma unroll
        for (int nt = 0; nt < 3; ++nt) {
          u32x2 xo = *(const u32x2*)(pXT + mi*16*XS_S + nt*16);
          float v0 = acc[mi][nt][0] + ob4[nt].x + blo(xo.x);
          float v1 = acc[mi][nt][1] + ob4[nt].y + bhi(xo.x);
          float v2 = acc[mi][nt][2] + ob4[nt].z + blo(xo.y);
          float v3 = acc[mi][nt][3] + ob4[nt].w + bhi(xo.y);
          acc[mi][nt][0] = v0; acc[mi][nt][1] = v1;
          acc[mi][nt][2] = v2; acc[mi][nt][3] = v3;
          s1 += (v0+v1)+(v2+v3);
          s2 += v0*v0; s2 += v1*v1; s2 += v2*v2; s2 += v3*v3;
        }
        s1 += __shfl_xor(s1,16); s2 += __shfl_xor(s2,16);
        s1 += __shfl_xor(s1,32); s2 += __shfl_xor(s2,32);
        if (lg == 0) {
          float2 pr; pr.x = s1; pr.y = s2;
          *(float2*)&rowred[row*8 + wn*2] = pr;
        }
      }
    }
    __syncthreads();
#pragma unroll
    for (int mi = 0; mi < 3; ++mi) {
      if (wm < 2 || mi == 0) {
        const int row = wm*48 + mi*16 + lr;
        float4 q0 = *(const float4*)&rowred[row*8];
        float4 q1 = *(const float4*)&rowred[row*8 + 4];
        float S1 = (q0.x + q0.z) + (q1.x + q1.z);
        float S2 = (q0.y + q0.w) + (q1.y + q1.w);
        float mean = S1 * (1.0f/DIMM);
        float var  = S2 * (1.0f/DIMM) - mean*mean;
        float rs = rsqrtf(var + 1e-5f);
        if (row < NTOK) {
#pragma unroll
          for (int nt = 0; nt < 3; ++nt) {
            f4 y;
            y[0] = (acc[mi][nt][0]-mean)*rs*g4[nt].x + b4[nt].x;
            y[1] = (acc[mi][nt][1]-mean)*rs*g4[nt].y + b4[nt].y;
            y[2] = (acc[mi][nt][2]-mean)*rs*g4[nt].z + b4[nt].z;
            y[3] = (acc[mi][nt][3]-mean)*rs*g4[nt].w + b4[nt].w;
            *(u32x2*)(pXT + mi*16*XS_S + nt*16) = pack4(y);
          }
        }
      }
    }
    __syncthreads();
  };

  // ---- patch embed: stage img (shifted +1 row; row0 = cls slot) into QH region ----
  const float* imgb = img + (size_t)b * (TIMG*FIMG);
  for (int i = tid; i < TIMG*FIMG; i += 768) {
    int r = i / FIMG, c = i - r*FIMG;
    sm[QH0 + (r+1)*QH_S + c] = f2b(imgb[i]);
  }
  __syncthreads();
  {
    const u16* wl = wlin + (size_t)(wn*3)*2*512 + lane*8;
    bf8 Bf[3][2];
#pragma unroll
    for (int nt = 0; nt < 3; ++nt)
#pragma unroll
      for (int kt = 0; kt < 2; ++kt)
        Bf[nt][kt] = *(const bf8*)&wl[(nt*2+kt)*512];
#pragma unroll
    for (int mi = 0; mi < 3; ++mi) {
      if (wm < 2 || mi == 0) {
        bf8 Af[2];
#pragma unroll
        for (int kt = 0; kt < 2; ++kt)
          Af[kt] = *(const bf8*)&pOA[mi*16*QH_S + kt*32];
#pragma unroll
        for (int nt = 0; nt < 3; ++nt) {
          f4 a = zero4;
#pragma unroll
          for (int kt = 0; kt < 2; ++kt) a = mm(Af[kt], Bf[nt][kt], a);
          int col = wn*48 + nt*16 + lr;
#pragma unroll
          for (int r = 0; r < 4; ++r) {
            int row = wm*48 + mi*16 + lg*4 + r;
            if (row < NTOK) {
              float v = a[r] + pos_emb[row*DIMM + col] + (row==0 ? g_feat[col] : 0.f);
              pXE[(mi*16+r)*XS_S + nt*16] = f2b(v);
            }
          }
        }
      }
    }
  }
  __syncthreads();

  for (int L = 0; L < DEPTH; ++L) {
    const u16* wq = wqkv + (size_t)L*36*6*512;
    // ================= attention =================
    f4 oacc[3][3];
#pragma unroll
    for (int mi = 0; mi < 3; ++mi)
#pragma unroll
      for (int nt = 0; nt < 3; ++nt) oacc[mi][nt] = zero4;

    for (int h = 0; h < NHEAD; ++h) {
      // (A1) fused Q+K pass: A-frags read ONCE, feed both transposed GEMMs
      {
        const u16* wpq = wq + ((size_t)(     h*4 + wn)*6)*512 + lane*8;
        const u16* wpk = wq + ((size_t)(12 + h*4 + wn)*6)*512 + lane*8;
        bf8 Bq[6], Bk[6];
#pragma unroll
        for (int kt = 0; kt < 6; ++kt) {
          Bq[kt] = *(const bf8*)&wpq[kt*512];
          Bk[kt] = *(const bf8*)&wpk[kt*512];
        }
#pragma unroll
        for (int mi = 0; mi < 3; ++mi) {
          if (wm < 2 || mi == 0) {
            bf8 Af[6];
#pragma unroll
            for (int kt = 0; kt < 6; ++kt)
              Af[kt] = *(const bf8*)&pA[mi*16*XS_S + kt*32];
            f4 aq = zero4, ak = zero4;
#pragma unroll
            for (int kt = 0; kt < 6; ++kt) {
              aq = mm(Bq[kt], Af[kt], aq);   // (xWq)^T
              ak = mm(Bk[kt], Af[kt], ak);   // (xWk)^T
            }
            aq = aq * QSCALE;                // Q pre-scaled (incl log2e)
            *(u32x2*)(pQS + mi*16*QH_S) = pack4(aq);
            *(u32x2*)(pQS + (KH0-QH0) + mi*16*QH_S) = pack4(ak);
          }
        }
      }
      // (A2) V pass (normal orientation; transposed dest, b64)
      {
        const u16* wpv = wq + ((size_t)(24 + h*4 + wn)*6)*512 + lane*8;
        bf8 Bv[6];
#pragma unroll
        for (int kt = 0; kt < 6; ++kt) Bv[kt] = *(const bf8*)&wpv[kt*512];
#pragma unroll
        for (int mi = 0; mi < 3; ++mi) {
          if (wm < 2 || mi == 0) {
            bf8 Af[6];
#pragma unroll
            for (int kt = 0; kt < 6; ++kt)
              Af[kt] = *(const bf8*)&pA[mi*16*XS_S + kt*32];
            f4 av = zero4;
#pragma unroll
            for (int kt = 0; kt < 6; ++kt) av = mm(Af[kt], Bv[kt], av);
            *(u32x2*)(pVS + mi*16) = pack4(av);
          }
        }
      }
      __syncthreads();

      // HOISTED: out-proj B-fragments loaded HERE so their L2 latency hides under
      // phase B (waves 0-6) or the barrier wait (waves 7-11).
      bf8 Bo[3][2];
      {
        const u16* wp = wout + (((size_t)(L*12 + wn*3)*6) + h*2)*512 + lane*8;
#pragma unroll
        for (int nt = 0; nt < 3; ++nt)
#pragma unroll
          for (int ks = 0; ks < 2; ++ks)
            Bo[nt][ks] = *(const bf8*)&wp[(nt*6 + ks)*512];
      }

      // (B): S^T = K·Q^T per key-tile; softmax lane-local over keys; P b64; O = (PV)^T
      if (wv < MT) {
        bf8 Aq[2];
#pragma unroll
        for (int ks = 0; ks < 2; ++ks)
          Aq[ks] = *(const bf8*)&pQA[ks*32];
        f4 sT[7];                      // sT[kt][r]: key kt*16+lg*4+r, query lr
#pragma unroll
        for (int kt = 0; kt < 7; ++kt) {
          f4 a = zero4;
#pragma unroll
          for (int ks = 0; ks < 2; ++ks) {
            bf8 Bk2 = *(const bf8*)&pKB[kt*16*QH_S + ks*32];
            a = mm(Bk2, Aq[ks], a);    // S^T
          }
          sT[kt] = a;
        }
        // keys valid: kt<6 all; kt==6 only lg==0 && r<3 (keys 96..98)
        float m = -1e30f;
#pragma unroll
        for (int kt = 0; kt < 6; ++kt)
#pragma unroll
          for (int r = 0; r < 4; ++r) m = fmaxf(m, sT[kt][r]);
        if (lg == 0) { m = fmaxf(m, fmaxf(sT[6][0], fmaxf(sT[6][1], sT[6][2]))); }
        m = fmaxf(m, __shfl_xor(m, 16));
        m = fmaxf(m, __shfl_xor(m, 32));
        float pT[7][4]; float sum = 0.f;
#pragma unroll
        for (int kt = 0; kt < 6; ++kt)
#pragma unroll
          for (int r = 0; r < 4; ++r) { float p = exp2f(sT[kt][r] - m); pT[kt][r] = p; sum += p; }
#pragma unroll
        for (int r = 0; r < 4; ++r) {
          float p = (lg == 0 && r < 3) ? exp2f(sT[6][r] - m) : 0.f;
          pT[6][r] = p; sum += p;
        }
        sum += __shfl_xor(sum, 16);
        sum += __shfl_xor(sum, 32);
        float inv = 1.0f / sum;
#pragma unroll
        for (int kt = 0; kt < 7; ++kt) {
          f4 pp;
          pp[0] = pT[kt][0]*inv; pp[1] = pT[kt][1]*inv;
          pp[2] = pT[kt][2]*inv; pp[3] = pT[kt][3]*inv;
          *(u32x2*)(pPT + kt*16) = pack4(pp);
        }
        asm volatile("" ::: "memory");  // keep P writes before fragment reads
        bf8 Ap[4];
#pragma unroll
        for (int ks = 0; ks < 4; ++ks)
          Ap[ks] = *(const bf8*)&pPA[ks*32];
#pragma unroll
        for (int nt = 0; nt < 4; ++nt) {
          f4 a = zero4;
#pragma unroll
          for (int ks = 0; ks < 4; ++ks) {
            bf8 Bv2 = *(const bf8*)&pVB[nt*16*VT_S + ks*32];
            a = mm(Bv2, Ap[ks], a);    // (PV)^T
          }
          *(u32x2*)(pOS + nt*16) = pack4(a);  // o[qtoken][dhead] b64
        }
      }
      __syncthreads();

      // (D) out-proj TRANSPOSED accumulate: oaccT += (o_h · out_w)^T  (Bo pre-loaded)
      {
#pragma unroll
        for (int mi = 0; mi < 3; ++mi) {
          if (wm < 2 || mi == 0) {
            bf8 Ao[2];
#pragma unroll
            for (int ks = 0; ks < 2; ++ks)
              Ao[ks] = *(const bf8*)&pOA[mi*16*QH_S + ks*32];
#pragma unroll
            for (int nt = 0; nt < 3; ++nt)
#pragma unroll
              for (int ks = 0; ks < 2; ++ks)
                oacc[mi][nt] = mm(Bo[nt][ks], Ao[ks], oacc[mi][nt]);
          }
        }
      }
      __syncthreads();
    } // heads

    epilogue_ln(oacc, ln1_g + L*DIMM, ln1_b + L*DIMM, out_b + L*DIMM);

    // ================= MLP =================
    f4 facc[3][3];
#pragma unroll
    for (int mi = 0; mi < 3; ++mi)
#pragma unroll
      for (int nt = 0; nt < 3; ++nt) facc[mi][nt] = zero4;

    for (int blk = 0; blk < 4; ++blk) {
      { // GEMM1 + gelu, TRANSPOSED -> h[token][mlpcol] b64 stores (nt-outer, B[6] only)
        const u16* wp = wff1 + ((size_t)(L*48 + blk*12 + wn*3)*6)*512 + lane*8;
        const float* fbp = ff1_b + L*MLPD + blk*192 + wn*48;
#pragma unroll
        for (int nt = 0; nt < 3; ++nt) {
          bf8 B[6];
#pragma unroll
          for (int kt = 0; kt < 6; ++kt) B[kt] = *(const bf8*)&wp[(nt*6+kt)*512];
          float4 fb4 = *(const float4*)&fbp[nt*16 + lg*4];
#pragma unroll
          for (int mi = 0; mi < 3; ++mi) {
            if (wm < 2 || mi == 0) {
              bf8 Af[6];
#pragma unroll
              for (int kt = 0; kt < 6; ++kt)
                Af[kt] = *(const bf8*)&pA[mi*16*XS_S + kt*32];
              f4 a = zero4;
#pragma unroll
              for (int kt = 0; kt < 6; ++kt) a = mm(B[kt], Af[kt], a);  // (xW1)^T
              *(u32x2*)(pHS + mi*16*XS_S + nt*16) = pack4(gelu4(a, fb4));
            }
          }
        }
      }
      __syncthreads();
      { // GEMM2 TRANSPOSED accumulate; B-pair holding (no gelu temps: spill-safe)
        const u16* wp = wff2 + ((size_t)(L*12 + wn*3)*24 + blk*6)*512 + lane*8;
        { // group nt = {0,1}
          bf8 B0[6], B1[6];
#pragma unroll
          for (int kt = 0; kt < 6; ++kt) {
            B0[kt] = *(const bf8*)&wp[kt*512];
            B1[kt] = *(const bf8*)&wp[(24+kt)*512];
          }
#pragma unroll
          for (int mi = 0; mi < 3; ++mi) {
            if (wm < 2 || mi == 0) {
              bf8 Ah[6];
#pragma unroll
              for (int kt = 0; kt < 6; ++kt)
                Ah[kt] = *(const bf8*)&pH[mi*16*XS_S + kt*32];
#pragma unroll
              for (int kt = 0; kt < 6; ++kt) {
                facc[mi][0] = mm(B0[kt], Ah[kt], facc[mi][0]);
                facc[mi][1] = mm(B1[kt], Ah[kt], facc[mi][1]);
              }
            }
          }
        }
        { // group nt = {2}
          bf8 B2[6];
#pragma unroll
          for (int kt = 0; kt < 6; ++kt)
            B2[kt] = *(const bf8*)&wp[(48+kt)*512];
#pragma unroll
          for (int mi = 0; mi < 3; ++mi) {
            if (wm < 2 || mi == 0) {
              bf8 Ah[6];
#pragma unroll
              for (int kt = 0; kt < 6; ++kt)
                Ah[kt] = *(const bf8*)&pH[mi*16*XS_S + kt*32];
#pragma unroll
              for (int kt = 0; kt < 6; ++kt)
                facc[mi][2] = mm(B2[kt], Ah[kt], facc[mi][2]);
            }
          }
        }
      }
      __syncthreads();
    }

    epilogue_ln(facc, ln2_g + L*DIMM, ln2_b + L*DIMM, ff2_b + L*DIMM);
  } // layers

  // ================= head =================
  float* yv = rowred;
  if (wv == 0) {
    float x0 = b2f(sm[XS0 + lane]);
    float x1 = b2f(sm[XS0 + 64 + lane]);
    float x2 = b2f(sm[XS0 + 128 + lane]);
    float s1 = x0+x1+x2;
    float s2 = x0*x0 + x1*x1 + x2*x2;
#pragma unroll
    for (int d = 1; d < 64; d <<= 1) { s1 += __shfl_xor(s1, d); s2 += __shfl_xor(s2, d); }
    float mean = s1*(1.0f/DIMM), var = s2*(1.0f/DIMM) - mean*mean;
    float rs = rsqrtf(var + 1e-5f);
    yv[lane]      = (x0-mean)*rs*hln_g[lane]      + hln_b[lane];
    yv[64+lane]   = (x1-mean)*rs*hln_g[64+lane]   + hln_b[64+lane];
    yv[128+lane]  = (x2-mean)*rs*hln_g[128+lane]  + hln_b[128+lane];
  }
  __syncthreads();
  if (tid < NCLS) {
    float acc = head_b[tid];
    for (int k = 0; k < DIMM; ++k) acc += yv[k] * head_w[k*NCLS + tid];
    out[(size_t)b*NCLS + tid] = acc;
  }
}

extern "C" void kernel_launch(void* const* d_in, const int* in_sizes, int n_in,
                              void* d_out, int out_size, void* d_ws, size_t ws_size,
                              hipStream_t stream) {
  const float* img    = (const float*)d_in[0];
  const float* lin_w  = (const float*)d_in[1];
  const float* g_feat = (const float*)d_in[2];
  const float* pos_emb= (const float*)d_in[3];
  const float* ln1_g  = (const float*)d_in[4];
  const float* ln1_b  = (const float*)d_in[5];
  const float* ln2_g  = (const float*)d_in[6];
  const float* ln2_b  = (const float*)d_in[7];
  const float* qkv_w  = (const float*)d_in[8];
  const float* out_w  = (const float*)d_in[9];
  const float* out_b  = (const float*)d_in[10];
  const float* ff1_w  = (const float*)d_in[11];
  const float* ff1_b  = (const float*)d_in[12];
  const float* ff2_w  = (const float*)d_in[13];
  const float* ff2_b  = (const float*)d_in[14];
  const float* hln_g  = (const float*)d_in[15];
  const float* hln_b  = (const float*)d_in[16];
  const float* head_w = (const float*)d_in[17];
  const float* head_b = (const float*)d_in[18];

  u16* ws   = (u16*)d_ws;
  u16* wlin = ws;                   // 1*12*2*512    = 12288
  u16* wqkv = wlin + 12288;         // 12*36*6*512   = 1327104
  u16* wout = wqkv + 1327104;       // 12*12*6*512   = 442368
  u16* wff1 = wout + 442368;        // 12*48*6*512   = 1769472
  u16* wff2 = wff1 + 1769472;       // 12*12*24*512  = 1769472

  struct PermArgs { const float* src; u16* dst; int layers, Kdim, Ndim, realK; };
  const PermArgs pa[5] = {
    { lin_w, wlin, 1, 64, 192, 40 },
    { qkv_w, wqkv, 12, 192, 576, 192 },
    { out_w, wout, 12, 192, 192, 192 },
    { ff1_w, wff1, 12, 192, 768, 192 },
    { ff2_w, wff2, 12, 768, 192, 768 },
  };
  for (int i = 0; i < 5; ++i) {
    int total = pa[i].layers * (pa[i].Ndim/16) * (pa[i].Kdim/32) * 512;
    hipLaunchKernelGGL(permw, dim3((total + 255)/256), dim3(256), 0, stream,
                       pa[i].src, pa[i].dst, total, pa[i].Kdim/32, pa[i].Ndim/16,
                       pa[i].realK, pa[i].Ndim);
  }

  hipFuncSetAttribute(reinterpret_cast<const void*>(vit_main),
                      hipFuncAttributeMaxDynamicSharedMemorySize, SMEM_BYTES);

  hipLaunchKernelGGL(vit_main, dim3(NBATCH), dim3(768), SMEM_BYTES, stream,
                     img, g_feat, pos_emb, ln1_g, ln1_b, ln2_g, ln2_b,
                     out_b, ff1_b, ff2_b, hln_g, hln_b, head_w, head_b,
                     wlin, wqkv, wout, wff1, wff2, (float*)d_out);
}